// Round 1
// baseline (1088.604 us; speedup 1.0000x reference)
//
#include <hip/hip_runtime.h>

typedef __attribute__((ext_vector_type(8))) short short8;
typedef __attribute__((ext_vector_type(4))) float f32x4;
typedef __attribute__((ext_vector_type(4))) unsigned int u32x4;

__device__ __forceinline__ unsigned short f2bf(float f) {
    unsigned u = __builtin_bit_cast(unsigned, f);
    u += 0x7fffu + ((u >> 16) & 1u);          // round-to-nearest-even
    return (unsigned short)(u >> 16);
}
__device__ __forceinline__ float bf2f(unsigned short h) {
    unsigned u = ((unsigned)h) << 16;
    return __builtin_bit_cast(float, u);
}
__device__ __forceinline__ unsigned pk2(float a, float b) {
    return (unsigned)f2bf(a) | ((unsigned)f2bf(b) << 16);
}
__device__ __forceinline__ float fast_tanh(float x) {
    // tanh(x) = 1 - 2/(exp2(x*2*log2e)+1); v_exp/v_rcp ~1ulp, plenty for 5.7e-2 tol
    float t = __builtin_amdgcn_exp2f(x * 2.885390081777927f);
    return 1.f - 2.f * __builtin_amdgcn_rcpf(t + 1.f);
}

// LDS layout (bytes):
//   XT   @0      [64][72] bf16 = 9216   (x tile, then t0 tile; later aliased as a1 store [2048] u32)
//   W0T  @9216   [64][72] bf16 = 9216   (cols = term*8+h, k = d; padded stride 72 => 2-way max)
//   W1T  @18432  [16][72] bf16 = 2304   (cols 8..15 garbage, masked in epilogue)
//   H1S  @20736  [2048][8] bf16 = 32768
//   A0T  @53504  [64][16] f32  = 4096
//   FP   @57600  float params/stats/reduction scratch
#define SMEM_BYTES 60352

__global__ __launch_bounds__(256, 2)
void aop_fused(const float* __restrict__ x,
               const float* __restrict__ W0, const float* __restrict__ b0,
               const float* __restrict__ g0, const float* __restrict__ be0,
               const float* __restrict__ Wa0, const float* __restrict__ ba0g,
               const float* __restrict__ ga0, const float* __restrict__ bea0,
               const float* __restrict__ W1, const float* __restrict__ b1,
               const float* __restrict__ g1, const float* __restrict__ be1,
               const float* __restrict__ Wa1, const float* __restrict__ ba1g,
               const float* __restrict__ ga1, const float* __restrict__ bea1,
               float* __restrict__ out)
{
    constexpr long O1 = 33554432L;   // aux1 base: 2048*8192*2
    constexpr long O2 = 37748736L;   // t0  base: O1 + 2048*1024*2
    constexpr long O3 = 171966464L;  // t1  base: O2 + 2048*8192*8
    constexpr float INV_B = 1.f / 2048.f;
    constexpr float EPS = 1e-5f;

    __shared__ __align__(16) char smem[SMEM_BYTES];
    unsigned short* XT  = (unsigned short*)(smem);
    unsigned short* W0T = (unsigned short*)(smem + 9216);
    unsigned short* W1T = (unsigned short*)(smem + 18432);
    unsigned short* H1S = (unsigned short*)(smem + 20736);
    float*          A0T = (float*)(smem + 53504);
    float*          FP  = (float*)(smem + 57600);
    float* b0v = FP;        float* g0v = FP + 64;  float* be0v = FP + 128;
    float* A0  = FP + 192;  float* B0  = FP + 256;
    float* wa0 = FP + 320;  /* 128 */
    float* ba0 = FP + 448;  /* 16 */
    float* Aa0 = FP + 464;  float* Ba0 = FP + 480;
    float* b1v = FP + 496;  float* g1v = FP + 504; float* be1v = FP + 512;
    float* A1  = FP + 520;  float* B1  = FP + 528;
    float* wa1 = FP + 536;  /* 16 */
    float* ba1 = FP + 552;  float* Aa1 = FP + 554; float* Ba1 = FP + 556;
    float* red = FP + 560;  /* 128 */
    unsigned* A1S = (unsigned*)(smem);   // alias over XT after phase 2

    const int tid  = threadIdx.x;
    const int lane = tid & 63;
    const int w    = tid >> 6;        // wave id 0..3
    const int l15  = tid & 15;
    const int q    = (tid >> 4) & 3;  // quad within wave
    const int r    = blockIdx.x;      // root term
    const int c0   = w * 16;          // this wave's column base (of 64)

    // ---------------- prologue: stage weights/params ----------------
    {
        const float4* W0g = (const float4*)(W0 + (long)r * 4096);
        for (int i = tid; i < 1024; i += 256) {
            float4 v = W0g[i];
            int t = i >> 7, rem = i & 127;
            int d = rem >> 1, hh = (rem & 1) * 4;
            int cb = t * 8 + hh;
            W0T[(cb + 0) * 72 + d] = f2bf(v.x);
            W0T[(cb + 1) * 72 + d] = f2bf(v.y);
            W0T[(cb + 2) * 72 + d] = f2bf(v.z);
            W0T[(cb + 3) * 72 + d] = f2bf(v.w);
        }
        const float4* W1g = (const float4*)(W1 + (long)r * 512);
        for (int i = tid; i < 128; i += 256) {
            float4 v = W1g[i];
            int flat = i * 4; int d = flat >> 3; int hh = flat & 7;
            W1T[(hh + 0) * 72 + d] = f2bf(v.x);
            W1T[(hh + 1) * 72 + d] = f2bf(v.y);
            W1T[(hh + 2) * 72 + d] = f2bf(v.z);
            W1T[(hh + 3) * 72 + d] = f2bf(v.w);
        }
        if (tid < 64)       { b0v[tid] = b0[r*64 + tid]; g0v[tid] = g0[r*64 + tid]; be0v[tid] = be0[r*64 + tid]; }
        else if (tid < 192) { wa0[tid - 64] = Wa0[(long)r*128 + tid - 64]; }
        else if (tid < 208) { ba0[tid - 192] = ba0g[(long)r*16 + tid - 192]; }
        else if (tid < 216) { int i = tid - 208; b1v[i] = b1[r*8 + i]; g1v[i] = g1[r*8 + i]; be1v[i] = be1[r*8 + i]; }
        else if (tid < 232) { wa1[tid - 216] = Wa1[(long)r*16 + tid - 216]; }
        else if (tid < 234) { ba1[tid - 232] = ba1g[(long)r*2 + tid - 232]; }
    }
    __syncthreads();

    // stage one 64-row x tile (fp32 global -> bf16 LDS, padded stride 72)
    auto stage_x = [&](int tile) {
        int rr = tid >> 2, c16 = (tid & 3) << 4;
        const float4* xp = (const float4*)(x + ((long)(tile * 64 + rr)) * 64 + c16);
        float4 f0 = xp[0], f1 = xp[1], f2v = xp[2], f3 = xp[3];
        u32x4 u0, u1;
        u0[0] = pk2(f0.x, f0.y);  u0[1] = pk2(f0.z, f0.w);
        u0[2] = pk2(f1.x, f1.y);  u0[3] = pk2(f1.z, f1.w);
        u1[0] = pk2(f2v.x, f2v.y); u1[1] = pk2(f2v.z, f2v.w);
        u1[2] = pk2(f3.x, f3.y);  u1[3] = pk2(f3.z, f3.w);
        *(u32x4*)(XT + rr * 72 + c16)     = u0;
        *(u32x4*)(XT + rr * 72 + c16 + 8) = u1;
    };

    auto do_mfma0 = [&](f32x4* acc) {
        #pragma unroll
        for (int ks = 0; ks < 2; ++ks) {
            short8 bf = __builtin_bit_cast(short8,
                *(const u32x4*)(W0T + (c0 + l15) * 72 + ks * 32 + q * 8));
            #pragma unroll
            for (int rt = 0; rt < 4; ++rt) {
                short8 af = __builtin_bit_cast(short8,
                    *(const u32x4*)(XT + (rt * 16 + l15) * 72 + ks * 32 + q * 8));
                acc[rt] = __builtin_amdgcn_mfma_f32_16x16x32_bf16(af, bf, acc[rt], 0, 0, 0);
            }
        }
    };

    const f32x4 vzero = {0.f, 0.f, 0.f, 0.f};

    // ---------------- phase 1: h0 batch stats ----------------
    float s0 = 0.f, q0 = 0.f;
    const float b0c = b0v[c0 + l15];
    for (int tile = 0; tile < 32; ++tile) {
        stage_x(tile);
        __syncthreads();
        f32x4 acc[4] = {vzero, vzero, vzero, vzero};
        do_mfma0(acc);
        #pragma unroll
        for (int rt = 0; rt < 4; ++rt)
            #pragma unroll
            for (int e = 0; e < 4; ++e) {
                float v = fast_tanh(acc[rt][e] + b0c);
                s0 += v; q0 += v * v;
            }
        __syncthreads();
    }
    s0 += __shfl_xor(s0, 16); s0 += __shfl_xor(s0, 32);
    q0 += __shfl_xor(q0, 16); q0 += __shfl_xor(q0, 32);
    if (lane < 16) {
        int c = c0 + lane;
        float mu = s0 * INV_B, var = q0 * INV_B - mu * mu;
        float rs = __builtin_amdgcn_rsqf(var + EPS);
        float a = g0v[c] * rs;
        A0[c] = a; B0[c] = be0v[c] - a * mu;
    }
    __syncthreads();

    // ---------------- phase 2: t0 + layer1 h1 + raw aux0 ----------------
    const float A0c = A0[c0 + l15], B0c = B0[c0 + l15];
    const bool  colOK = (l15 < 8);
    const float b1c = colOK ? b1v[l15] : 0.f;
    float s1 = 0.f, q1 = 0.f;
    float sa0 = 0.f, sq0 = 0.f, sa1 = 0.f, sq1 = 0.f;
    const int tau = tid >> 5, jj = tid & 31;

    for (int tile = 0; tile < 32; ++tile) {
        const int br = tile * 64;
        stage_x(tile);
        __syncthreads();
        f32x4 acc[4] = {vzero, vzero, vzero, vzero};
        do_mfma0(acc);
        __syncthreads();                       // everyone done reading x tile
        #pragma unroll
        for (int rt = 0; rt < 4; ++rt)
            #pragma unroll
            for (int e = 0; e < 4; ++e) {
                float h  = fast_tanh(acc[rt][e] + b0c);
                float t0v = A0c * h + B0c;
                int row = rt * 16 + q * 4 + e;
                out[O2 + (long)(br + row) * 65536 + (long)r * 64 + c0 + l15] = t0v;
                XT[row * 72 + c0 + l15] = f2bf(t0v);   // t0 tile for layer1/aux0
            }
        __syncthreads();                       // t0 tile complete
        // layer 1: wave w handles rows [w*16, w*16+16) of the tile, K=64
        f32x4 c1 = vzero;
        #pragma unroll
        for (int ks = 0; ks < 2; ++ks) {
            short8 af = __builtin_bit_cast(short8,
                *(const u32x4*)(XT + (w * 16 + l15) * 72 + ks * 32 + q * 8));
            short8 bfr = __builtin_bit_cast(short8,
                *(const u32x4*)(W1T + l15 * 72 + ks * 32 + q * 8));
            c1 = __builtin_amdgcn_mfma_f32_16x16x32_bf16(af, bfr, c1, 0, 0, 0);
        }
        if (colOK) {
            #pragma unroll
            for (int e = 0; e < 4; ++e) {
                float hv = fast_tanh(c1[e] + b1c);
                s1 += hv; q1 += hv * hv;
                H1S[(br + w * 16 + q * 4 + e) * 8 + l15] = f2bf(hv);
            }
        }
        // aux0: thread -> term tau, rows {2jj, 2jj+1} of tile
        #pragma unroll
        for (int rr2 = 0; rr2 < 2; ++rr2) {
            int row = jj * 2 + rr2;
            u32x4 tv = *(const u32x4*)(XT + row * 72 + tau * 8);
            float p0 = ba0[tau * 2], p1 = ba0[tau * 2 + 1];
            #pragma unroll
            for (int hp = 0; hp < 4; ++hp) {
                unsigned uu = tv[hp];
                float fa = bf2f((unsigned short)(uu & 0xffffu));
                float fb = bf2f((unsigned short)(uu >> 16));
                int h = hp * 2;
                p0 += fa * wa0[tau * 16 + h * 2]     + fb * wa0[tau * 16 + (h + 1) * 2];
                p1 += fa * wa0[tau * 16 + h * 2 + 1] + fb * wa0[tau * 16 + (h + 1) * 2 + 1];
            }
            float av0 = fast_tanh(p0), av1 = fast_tanh(p1);
            sa0 += av0; sq0 += av0 * av0; sa1 += av1; sq1 += av1 * av1;
            A0T[row * 16 + tau * 2]     = av0;
            A0T[row * 16 + tau * 2 + 1] = av1;
        }
        __syncthreads();                       // a0 tile complete
        {   // cooperative contiguous store of raw a0 (rewritten in phase 5)
            int row = tid >> 2, p = tid & 3;
            float4 v = *(const float4*)(A0T + row * 16 + p * 4);
            *(float4*)(out + (long)(br + row) * 16384 + (long)r * 16 + p * 4) = v;
        }
    }

    // ---- finalize h1 / aux0 stats ----
    s1 += __shfl_xor(s1, 16); s1 += __shfl_xor(s1, 32);
    q1 += __shfl_xor(q1, 16); q1 += __shfl_xor(q1, 32);
    if (lane < 8) { red[w * 8 + lane] = s1; red[32 + w * 8 + lane] = q1; }
    #pragma unroll
    for (int d = 1; d < 32; d <<= 1) {
        sa0 += __shfl_xor(sa0, d); sq0 += __shfl_xor(sq0, d);
        sa1 += __shfl_xor(sa1, d); sq1 += __shfl_xor(sq1, d);
    }
    if (jj == 0) {
        red[64 + tau * 4 + 0] = sa0; red[64 + tau * 4 + 1] = sq0;
        red[64 + tau * 4 + 2] = sa1; red[64 + tau * 4 + 3] = sq1;
    }
    __syncthreads();
    if (tid < 8) {
        float S = red[tid] + red[8 + tid] + red[16 + tid] + red[24 + tid];
        float Q = red[32 + tid] + red[40 + tid] + red[48 + tid] + red[56 + tid];
        float mu = S * INV_B, var = Q * INV_B - mu * mu;
        float rs = __builtin_amdgcn_rsqf(var + EPS);
        float g = g1v[tid];
        A1[tid] = g * rs; B1[tid] = be1v[tid] - g * rs * mu;
    } else if (tid >= 16 && tid < 32) {
        int idx = tid - 16; int tt = idx >> 1; int k = idx & 1;
        float S = red[64 + tt * 4 + k * 2], Q = red[64 + tt * 4 + k * 2 + 1];
        float mu = S * INV_B, var = Q * INV_B - mu * mu;
        float rs = __builtin_amdgcn_rsqf(var + EPS);
        float g = ga0[(long)r * 16 + idx];
        Aa0[idx] = g * rs; Ba0[idx] = bea0[(long)r * 16 + idx] - g * rs * mu;
    }
    __syncthreads();

    // ---------------- phase 3: t1 store + a1 + a1 stats ----------------
    float s2s0 = 0.f, s2q0 = 0.f, s2s1 = 0.f, s2q1 = 0.f;
    for (int it = 0; it < 8; ++it) {
        int b = it * 256 + tid;
        u32x4 hv = *(const u32x4*)(H1S + b * 8);
        float t1v[8];
        #pragma unroll
        for (int hp = 0; hp < 4; ++hp) {
            unsigned uu = hv[hp];
            t1v[hp * 2]     = A1[hp * 2]     * bf2f((unsigned short)(uu & 0xffffu)) + B1[hp * 2];
            t1v[hp * 2 + 1] = A1[hp * 2 + 1] * bf2f((unsigned short)(uu >> 16))     + B1[hp * 2 + 1];
        }
        float4 o0 = {t1v[0], t1v[1], t1v[2], t1v[3]};
        float4 o1 = {t1v[4], t1v[5], t1v[6], t1v[7]};
        *(float4*)(out + O3 + (long)b * 8192 + (long)r * 8)     = o0;
        *(float4*)(out + O3 + (long)b * 8192 + (long)r * 8 + 4) = o1;
        float p0 = ba1[0], p1 = ba1[1];
        #pragma unroll
        for (int h = 0; h < 8; ++h) { p0 += t1v[h] * wa1[h * 2]; p1 += t1v[h] * wa1[h * 2 + 1]; }
        float a10 = fast_tanh(p0), a11 = fast_tanh(p1);
        s2s0 += a10; s2q0 += a10 * a10; s2s1 += a11; s2q1 += a11 * a11;
        A1S[b] = pk2(a10, a11);     // alias over XT (free after phase 2)
    }
    #pragma unroll
    for (int d = 1; d < 64; d <<= 1) {
        s2s0 += __shfl_xor(s2s0, d); s2q0 += __shfl_xor(s2q0, d);
        s2s1 += __shfl_xor(s2s1, d); s2q1 += __shfl_xor(s2q1, d);
    }
    if (lane == 0) {
        red[96 + w * 4 + 0] = s2s0; red[96 + w * 4 + 1] = s2q0;
        red[96 + w * 4 + 2] = s2s1; red[96 + w * 4 + 3] = s2q1;
    }
    __syncthreads();
    if (tid < 2) {
        int k = tid;
        float S = red[96 + k * 2] + red[100 + k * 2] + red[104 + k * 2] + red[108 + k * 2];
        float Q = red[97 + k * 2] + red[101 + k * 2] + red[105 + k * 2] + red[109 + k * 2];
        float mu = S * INV_B, var = Q * INV_B - mu * mu;
        float rs = __builtin_amdgcn_rsqf(var + EPS);
        float g = ga1[(long)r * 2 + k];
        Aa1[k] = g * rs; Ba1[k] = bea1[(long)r * 2 + k] - g * rs * mu;
    }
    __syncthreads();

    // ---------------- phase 4: aux1 ----------------
    {
        float a0v = Aa1[0], b0vv = Ba1[0], a1v = Aa1[1], b1vv = Ba1[1];
        for (int it = 0; it < 8; ++it) {
            int b = it * 256 + tid;
            unsigned u = A1S[b];
            float x0 = bf2f((unsigned short)(u & 0xffffu));
            float x1 = bf2f((unsigned short)(u >> 16));
            float2 o = {a0v * x0 + b0vv, a1v * x1 + b1vv};
            *(float2*)(out + O1 + (long)b * 2048 + (long)r * 2) = o;
        }
    }

    // ---------------- phase 5: aux0 in-place affine rewrite ----------------
    __threadfence_block();
    for (int it = 0; it < 128; ++it) {
        int flat = it * 256 + tid;
        int b = flat >> 4, j = flat & 15;
        long adr = (long)b * 16384 + (long)r * 16 + j;
        float v = out[adr];
        out[adr] = Aa0[j] * v + Ba0[j];
    }
}

extern "C" void kernel_launch(void* const* d_in, const int* in_sizes, int n_in,
                              void* d_out, int out_size, void* d_ws, size_t ws_size,
                              hipStream_t stream) {
    (void)in_sizes; (void)n_in; (void)d_ws; (void)ws_size; (void)out_size;
    const float* x    = (const float*)d_in[0];
    const float* W0   = (const float*)d_in[1];
    const float* b0   = (const float*)d_in[2];
    const float* g0   = (const float*)d_in[3];
    const float* be0  = (const float*)d_in[4];
    const float* Wa0  = (const float*)d_in[5];
    const float* ba0  = (const float*)d_in[6];
    const float* ga0  = (const float*)d_in[7];
    const float* bea0 = (const float*)d_in[8];
    const float* W1   = (const float*)d_in[9];
    const float* b1   = (const float*)d_in[10];
    const float* g1   = (const float*)d_in[11];
    const float* be1  = (const float*)d_in[12];
    const float* Wa1  = (const float*)d_in[13];
    const float* ba1  = (const float*)d_in[14];
    const float* ga1  = (const float*)d_in[15];
    const float* bea1 = (const float*)d_in[16];
    aop_fused<<<dim3(1024), dim3(256), 0, stream>>>(
        x, W0, b0, g0, be0, Wa0, ba0, ga0, bea0,
        W1, b1, g1, be1, Wa1, ba1, ga1, bea1, (float*)d_out);
}